// Round 10
// baseline (312.044 us; speedup 1.0000x reference)
//
#include <hip/hip_runtime.h>
#include <hip/hip_bf16.h>

#define LL 1024
#define HID 768
#define NH 12
#define HD 64
#define KAUG 192   // 64 (q/8 or k) + 64 e1 + 64 e2
#define NBH 48     // B*NH

typedef unsigned int u32;
typedef unsigned short u16;
typedef __bf16 bf16_t;
typedef bf16_t bf16x8 __attribute__((ext_vector_type(8)));
typedef float f32x4 __attribute__((ext_vector_type(4)));
typedef u32 u32x4 __attribute__((ext_vector_type(4)));

__device__ __forceinline__ u16 f2b(float f) {
    union { float f; u32 u; } v; v.f = f;
    u32 r = v.u + 0x7fffu + ((v.u >> 16) & 1u);
    return (u16)(r >> 16);
}
__device__ __forceinline__ bf16x8 load8s(const u16* p) {  // LDS/global, 16B aligned
    return __builtin_bit_cast(bf16x8, *reinterpret_cast<const u32x4*>(p));
}
__device__ __forceinline__ void cvt4_store_v(u16* dst, float4 f) {
    ushort4 o;
    o.x = f2b(f.x); o.y = f2b(f.y); o.z = f2b(f.z); o.w = f2b(f.w);
    *reinterpret_cast<ushort4*>(dst) = o;
}

// ---------------------------------------------------------------- A2: QKV projections (MFMA, f32 in -> bf16 ws)
// Software-pipelined staging: next k-tile's f32 loads issued before current MFMA.
// Q/K written row-major augmented [bh][l][KAUG]; V written TRANSPOSED [bh][d][1024].
__global__ __launch_bounds__(256) void k_qkv(const float* __restrict__ hs,
                                             const float* __restrict__ Wq, const float* __restrict__ Wk,
                                             const float* __restrict__ Wv,
                                             const float* __restrict__ bq, const float* __restrict__ bk,
                                             const float* __restrict__ bv,
                                             u16* __restrict__ Qa, u16* __restrict__ Ka,
                                             u16* __restrict__ Vt) {
    __shared__ __align__(16) u16 smem[18432];
    u16* a_s = smem;                 // [row][col] stride 72
    u16* b_s = smem + 9216;
    int m0 = blockIdx.x * 128;
    int nt = blockIdx.y;                 // 0..17 ; 6 tiles per W
    int which = nt / 6;                  // 0=q 1=k 2=v
    int n0w = (nt % 6) * 128;
    const float* W    = (which == 0) ? Wq : (which == 1) ? Wk : Wv;
    const float* bias = (which == 0) ? bq : (which == 1) ? bk : bv;
    int tid = threadIdx.x;
    int wave = tid >> 6, lane = tid & 63, l15 = lane & 15, qd = lane >> 4;
    int wm = wave >> 1, wn = wave & 1;

    int srow = tid >> 4, scol = (tid & 15) * 4;   // this thread's staging coords (8 rows apart per it)

    f32x4 acc[4][4];
    for (int i = 0; i < 4; i++)
        for (int j = 0; j < 4; j++) acc[i][j] = f32x4{0.f, 0.f, 0.f, 0.f};

    float4 pa[8], pb[8];
    // preload k-tile 0
#pragma unroll
    for (int it = 0; it < 8; it++) {
        int row = srow + it * 16;
        pa[it] = *reinterpret_cast<const float4*>(&hs[(size_t)(m0 + row) * 768 + scol]);
        pb[it] = *reinterpret_cast<const float4*>(&W[(size_t)(n0w + row) * 768 + scol]);
    }
    for (int k0 = 0; k0 < 768; k0 += 64) {
        __syncthreads();                 // prior MFMA LDS reads complete
#pragma unroll
        for (int it = 0; it < 8; it++) {
            int row = srow + it * 16;
            cvt4_store_v(&a_s[row * 72 + scol], pa[it]);
            cvt4_store_v(&b_s[row * 72 + scol], pb[it]);
        }
        __syncthreads();
        if (k0 < 704) {                  // issue next tile's loads NOW (consumed next iter)
            int k1 = k0 + 64;
#pragma unroll
            for (int it = 0; it < 8; it++) {
                int row = srow + it * 16;
                pa[it] = *reinterpret_cast<const float4*>(&hs[(size_t)(m0 + row) * 768 + k1 + scol]);
                pb[it] = *reinterpret_cast<const float4*>(&W[(size_t)(n0w + row) * 768 + k1 + scol]);
            }
        }
        for (int kk = 0; kk < 2; kk++) {
            bf16x8 af[4], bf[4];
            for (int i = 0; i < 4; i++) af[i] = load8s(&a_s[(wm * 64 + i * 16 + l15) * 72 + kk * 32 + qd * 8]);
            for (int j = 0; j < 4; j++) bf[j] = load8s(&b_s[(wn * 64 + j * 16 + l15) * 72 + kk * 32 + qd * 8]);
            for (int i = 0; i < 4; i++)
                for (int j = 0; j < 4; j++)
                    acc[i][j] = __builtin_amdgcn_mfma_f32_16x16x32_bf16(af[i], bf[j], acc[i][j], 0, 0, 0);
        }
    }
    __syncthreads();
    int b = m0 >> 10, l0b = m0 & 1023;
    if (which != 2) {
        float qscale = (which == 0) ? 0.125f : 1.0f;
        for (int i = 0; i < 4; i++) {
            int m_loc = wm * 64 + i * 16 + qd * 4;
            for (int j = 0; j < 4; j++) {
                int n_loc = wn * 64 + j * 16 + l15;
                float bv_ = bias[n0w + n_loc];
                for (int r = 0; r < 4; r++)
                    smem[(m_loc + r) * 136 + n_loc] = f2b((acc[i][j][r] + bv_) * qscale);
            }
        }
        __syncthreads();
        u16* dstbuf = (which == 0) ? Qa : Ka;
        for (int it = 0; it < 8; it++) {
            int c = tid + it * 256;
            int row = c >> 4, col = (c & 15) * 8;
            u32x4 w = *reinterpret_cast<u32x4*>(&smem[row * 136 + col]);
            int nn = n0w + col;
            int h = nn >> 6, d = nn & 63;
            size_t dst = ((size_t)(b * NH + h) * LL + (l0b + row)) * KAUG + d;
            *reinterpret_cast<u32x4*>(&dstbuf[dst]) = w;
        }
    } else {
        for (int i = 0; i < 4; i++) {
            int m_loc = wm * 64 + i * 16 + qd * 4;
            for (int j = 0; j < 4; j++) {
                int n_loc = wn * 64 + j * 16 + l15;
                float bv_ = bias[n0w + n_loc];
                for (int r = 0; r < 4; r++)
                    smem[n_loc * 136 + (m_loc + r)] = f2b(acc[i][j][r] + bv_);
            }
        }
        __syncthreads();
        for (int it = 0; it < 8; it++) {
            int c = tid + it * 256;
            int n = c >> 4, m_off = (c & 15) * 8;
            u32x4 w = *reinterpret_cast<u32x4*>(&smem[n * 136 + m_off]);
            int nn = n0w + n;
            int h = nn >> 6, d = nn & 63;
            size_t dst = ((size_t)(b * NH + h) * HD + d) * LL + (l0b + m_off);
            *reinterpret_cast<u32x4*>(&Vt[dst]) = w;
        }
    }
}

// ---------------------------------------------------------------- A3: histogram + pe = counts @ node_emb
__global__ __launch_bounds__(256) void k_pe(const int* __restrict__ rw,
                                            const int* __restrict__ arw,
                                            const float* __restrict__ node_emb,
                                            u16* __restrict__ Qa, u16* __restrict__ Ka) {
    int m = blockIdx.x;                  // b*L + l
    __shared__ int hist[64];
    __shared__ float c1[32], c2[32];
    int t = threadIdx.x;
    if (t < 64) hist[t] = 0;
    __syncthreads();
    if (t < 128) atomicAdd(&hist[rw[m * 128 + t] & 31], 1);
    else         atomicAdd(&hist[32 + (arw[m * 128 + (t - 128)] & 31)], 1);
    __syncthreads();
    if (t < 64) {
        if (t < 32) c1[t] = (float)hist[t];
        else        c2[t - 32] = (float)hist[t];
    }
    __syncthreads();
    int b = m >> 10, l = m & 1023;
    for (int c = t; c < 768; c += 256) {
        float s1 = 0.f, s2 = 0.f;
        for (int v = 0; v < 30; v++) {
            float ne = node_emb[v * 768 + c];
            s1 += c1[v] * ne;
            s2 += c2[v] * ne;
        }
        int h = c >> 6, d = c & 63;
        size_t base = ((size_t)(b * NH + h) * LL + l) * KAUG;
        u16 e1 = f2b(s1), e2 = f2b(s2);
        Qa[base + 64 + d] = e1;  Ka[base + 64 + d] = e1;
        Qa[base + 128 + d] = e2; Ka[base + 128 + d] = e2;
    }
}

// ---------------------------------------------------------------- B: fused MFMA flash attention, XCD-swizzled
// 1-D grid 768. All 12 head-blocks of one (b,itile) map to the SAME XCD so the
// shared distance slice + K/V streams are L2-resident (4MB/XCD, not cross-coherent
// but read-only here). gid = xcd + 8*(h + 12*ghi), group = xcd + 8*ghi.
__global__ __launch_bounds__(256) void k_attn(const u16* __restrict__ Qa, const u16* __restrict__ Ka,
                                              const u16* __restrict__ Vt,
                                              const int* __restrict__ distance,
                                              const float* __restrict__ dist_emb,
                                              const float* __restrict__ mask,
                                              void* __restrict__ outv, int f32mode) {
    __shared__ __align__(16) u16 ka_s[64][200];
    __shared__ __align__(16) u16 vt_s[64][72];
    __shared__ __align__(16) u16 p_s[4][16][72];
    __shared__ float distcol[2048];

    int gid = blockIdx.x;                // 0..767
    int xcd = gid & 7;
    int inner = gid >> 3;                // 0..95
    int h = inner % 12;
    int ghi = inner / 12;                // 0..7
    int group = xcd + 8 * ghi;           // 0..63 = (b, itile)
    int b = group >> 4, itile = group & 15;
    int bh = b * NH + h;
    int tid = threadIdx.x, wave = tid >> 6, lane = tid & 63, l15 = lane & 15, qd = lane >> 4;

    const u16* Qh = Qa + (size_t)bh * LL * KAUG;
    const u16* Kh = Ka + (size_t)bh * LL * KAUG;
    const u16* Vh = Vt + (size_t)bh * HD * LL;     // V^T: [d][1024]
    const int* distb = distance + (size_t)b * LL * LL;
    const float* maskb = mask + (size_t)b * LL;

    for (int t = tid; t < 2048; t += 256) distcol[t] = dist_emb[t * NH + h];

    int i0 = itile * 64 + wave * 16;
    bf16x8 aq[6];
    for (int ks = 0; ks < 6; ks++)
        aq[ks] = load8s(&Qh[(size_t)(i0 + l15) * KAUG + ks * 32 + qd * 8]);

    f32x4 o[4];
    for (int i = 0; i < 4; i++) o[i] = f32x4{0.f, 0.f, 0.f, 0.f};
    float m_i[4], l_i[4];
    for (int r = 0; r < 4; r++) { m_i[r] = -1e30f; l_i[r] = 0.f; }

    int dpre[16]; float mpre[4];
    for (int nf = 0; nf < 4; nf++) {
        int j_abs = nf * 16 + l15;
        mpre[nf] = maskb[j_abs];
        for (int r = 0; r < 4; r++)
            dpre[nf * 4 + r] = distb[(size_t)(i0 + qd * 4 + r) * LL + j_abs];
    }

    for (int jt = 0; jt < 16; jt++) {
        int j0 = jt * 64;
        int dcur[16]; float mcur[4];
        for (int u_ = 0; u_ < 16; u_++) dcur[u_] = dpre[u_];
        for (int u_ = 0; u_ < 4; u_++)  mcur[u_] = mpre[u_];
        if (jt < 15) {
            int j0n = j0 + 64;
            for (int nf = 0; nf < 4; nf++) {
                int j_abs = j0n + nf * 16 + l15;
                mpre[nf] = maskb[j_abs];
                for (int r = 0; r < 4; r++)
                    dpre[nf * 4 + r] = distb[(size_t)(i0 + qd * 4 + r) * LL + j_abs];
            }
        }
        __syncthreads();
        for (int it = 0; it < 6; it++) {
            int c = tid + it * 256;
            int row = c / 24, col = (c % 24) * 8;
            *reinterpret_cast<u32x4*>(&ka_s[row][col]) =
                *reinterpret_cast<const u32x4*>(&Kh[(size_t)(j0 + row) * KAUG + col]);
        }
        for (int it = 0; it < 2; it++) {
            int c = tid + it * 256;
            int d = c >> 3, col = (c & 7) * 8;
            *reinterpret_cast<u32x4*>(&vt_s[d][col]) =
                *reinterpret_cast<const u32x4*>(&Vh[(size_t)d * LL + j0 + col]);
        }
        __syncthreads();

        f32x4 s[4];
        for (int nf = 0; nf < 4; nf++) {
            f32x4 accv = f32x4{0.f, 0.f, 0.f, 0.f};
            for (int ks = 0; ks < 6; ks++) {
                bf16x8 bfrag = load8s(&ka_s[nf * 16 + l15][ks * 32 + qd * 8]);
                accv = __builtin_amdgcn_mfma_f32_16x16x32_bf16(aq[ks], bfrag, accv, 0, 0, 0);
            }
            s[nf] = accv;
        }
        for (int nf = 0; nf < 4; nf++)
            for (int r = 0; r < 4; r++)
                s[nf][r] += distcol[dcur[nf * 4 + r] + 1] + mcur[nf];
        float mx[4];
        for (int r = 0; r < 4; r++) {
            float v = fmaxf(fmaxf(s[0][r], s[1][r]), fmaxf(s[2][r], s[3][r]));
            for (int off = 1; off < 16; off <<= 1) v = fmaxf(v, __shfl_xor(v, off));
            mx[r] = v;
        }
        float alpha[4], rs[4];
        for (int r = 0; r < 4; r++) {
            float mnew = fmaxf(m_i[r], mx[r]);
            alpha[r] = __expf(m_i[r] - mnew);
            m_i[r] = mnew;
            rs[r] = 0.f;
        }
        for (int nf = 0; nf < 4; nf++)
            for (int r = 0; r < 4; r++) {
                float p = __expf(s[nf][r] - m_i[r]);
                rs[r] += p;
                p_s[wave][qd * 4 + r][nf * 16 + l15] = f2b(p);
            }
        for (int r = 0; r < 4; r++) {
            float v = rs[r];
            for (int off = 1; off < 16; off <<= 1) v += __shfl_xor(v, off);
            l_i[r] = l_i[r] * alpha[r] + v;
        }
        for (int df = 0; df < 4; df++)
            for (int r = 0; r < 4; r++) o[df][r] *= alpha[r];
        __builtin_amdgcn_sched_barrier(0);
        asm volatile("" ::: "memory");
        for (int kstep = 0; kstep < 2; kstep++) {
            bf16x8 ap = load8s(&p_s[wave][l15][kstep * 32 + qd * 8]);
            for (int df = 0; df < 4; df++) {
                bf16x8 bv_ = load8s(&vt_s[df * 16 + l15][kstep * 32 + qd * 8]);
                o[df] = __builtin_amdgcn_mfma_f32_16x16x32_bf16(ap, bv_, o[df], 0, 0, 0);
            }
        }
    }
    for (int df = 0; df < 4; df++) {
        int d = df * 16 + l15;
        for (int r = 0; r < 4; r++) {
            int i_abs = i0 + qd * 4 + r;
            float v = o[df][r] / l_i[r];
            size_t idx = ((size_t)(b * LL) + i_abs) * HID + h * 64 + d;
            if (f32mode) ((float*)outv)[idx] = v;
            else         ((u16*)outv)[idx] = f2b(v);
        }
    }
}

// ---------------------------------------------------------------- launch
extern "C" void kernel_launch(void* const* d_in, const int* in_sizes, int n_in,
                              void* d_out, int out_size, void* d_ws, size_t ws_size,
                              hipStream_t stream) {
    const float* hs       = (const float*)d_in[0];
    const float* mask     = (const float*)d_in[1];
    const float* Wq       = (const float*)d_in[2];
    const float* bq       = (const float*)d_in[3];
    const float* Wk       = (const float*)d_in[4];
    const float* bk       = (const float*)d_in[5];
    const float* Wv       = (const float*)d_in[6];
    const float* bv       = (const float*)d_in[7];
    const float* node_emb = (const float*)d_in[8];
    const float* dist_emb = (const float*)d_in[9];
    const int* distance   = (const int*)d_in[10];
    const int* rw         = (const int*)d_in[11];
    const int* arw        = (const int*)d_in[12];

    int f32mode = 0;
    {
        hipDeviceptr_t base = nullptr; size_t sz = 0;
        if (hipMemGetAddressRange(&base, &sz, (hipDeviceptr_t)d_out) == hipSuccess) {
            size_t off = (size_t)((char*)d_out - (char*)base);
            if (sz - off >= (size_t)out_size * 4u) f32mode = 1;
        }
    }

    u16* Qa = (u16*)d_ws;                            // 48*1024*192 bf16
    u16* Ka = Qa + (size_t)NBH * LL * KAUG;
    u16* Vt = Ka + (size_t)NBH * LL * KAUG;          // V^T: 48*64*1024 bf16

    k_qkv<<<dim3(32, 18), dim3(256), 0, stream>>>(hs, Wq, Wk, Wv, bq, bk, bv, Qa, Ka, Vt);
    k_pe<<<dim3(4096), dim3(256), 0, stream>>>(rw, arw, node_emb, Qa, Ka);
    k_attn<<<dim3(768), dim3(256), 0, stream>>>(Qa, Ka, Vt, distance, dist_emb, mask, d_out, f32mode);
}

// Round 11
// 250.101 us; speedup vs baseline: 1.2477x; 1.2477x over previous
//
#include <hip/hip_runtime.h>
#include <hip/hip_bf16.h>

#define LL 1024
#define HID 768
#define NH 12
#define HD 64
#define KAUG 192   // 64 (q/8 or k) + 64 e1 + 64 e2
#define NBH 48     // B*NH

typedef unsigned int u32;
typedef unsigned short u16;
typedef __bf16 bf16_t;
typedef bf16_t bf16x8 __attribute__((ext_vector_type(8)));
typedef float f32x4 __attribute__((ext_vector_type(4)));
typedef u32 u32x4 __attribute__((ext_vector_type(4)));

__device__ __forceinline__ u16 f2b(float f) {
    union { float f; u32 u; } v; v.f = f;
    u32 r = v.u + 0x7fffu + ((v.u >> 16) & 1u);
    return (u16)(r >> 16);
}
__device__ __forceinline__ bf16x8 load8s(const u16* p) {  // LDS/global, 16B aligned
    return __builtin_bit_cast(bf16x8, *reinterpret_cast<const u32x4*>(p));
}
__device__ __forceinline__ void cvt4_store_v(u16* dst, float4 f) {
    ushort4 o;
    o.x = f2b(f.x); o.y = f2b(f.y); o.z = f2b(f.z); o.w = f2b(f.w);
    *reinterpret_cast<ushort4*>(dst) = o;
}

// ---------------------------------------------------------------- A2: QKV projections (MFMA, reg-pipelined)
__global__ __launch_bounds__(256) void k_qkv(const float* __restrict__ hs,
                                             const float* __restrict__ Wq, const float* __restrict__ Wk,
                                             const float* __restrict__ Wv,
                                             const float* __restrict__ bq, const float* __restrict__ bk,
                                             const float* __restrict__ bv,
                                             u16* __restrict__ Qa, u16* __restrict__ Ka,
                                             u16* __restrict__ Vt) {
    __shared__ __align__(16) u16 smem[18432];
    u16* a_s = smem;                 // [row][col] stride 72
    u16* b_s = smem + 9216;
    int m0 = blockIdx.x * 128;
    int nt = blockIdx.y;                 // 0..17 ; 6 tiles per W
    int which = nt / 6;                  // 0=q 1=k 2=v
    int n0w = (nt % 6) * 128;
    const float* W    = (which == 0) ? Wq : (which == 1) ? Wk : Wv;
    const float* bias = (which == 0) ? bq : (which == 1) ? bk : bv;
    int tid = threadIdx.x;
    int wave = tid >> 6, lane = tid & 63, l15 = lane & 15, qd = lane >> 4;
    int wm = wave >> 1, wn = wave & 1;

    int srow = tid >> 4, scol = (tid & 15) * 4;

    f32x4 acc[4][4];
    for (int i = 0; i < 4; i++)
        for (int j = 0; j < 4; j++) acc[i][j] = f32x4{0.f, 0.f, 0.f, 0.f};

    float4 pa[8], pb[8];
#pragma unroll
    for (int it = 0; it < 8; it++) {
        int row = srow + it * 16;
        pa[it] = *reinterpret_cast<const float4*>(&hs[(size_t)(m0 + row) * 768 + scol]);
        pb[it] = *reinterpret_cast<const float4*>(&W[(size_t)(n0w + row) * 768 + scol]);
    }
    for (int k0 = 0; k0 < 768; k0 += 64) {
        __syncthreads();
#pragma unroll
        for (int it = 0; it < 8; it++) {
            int row = srow + it * 16;
            cvt4_store_v(&a_s[row * 72 + scol], pa[it]);
            cvt4_store_v(&b_s[row * 72 + scol], pb[it]);
        }
        __syncthreads();
        if (k0 < 704) {
            int k1 = k0 + 64;
#pragma unroll
            for (int it = 0; it < 8; it++) {
                int row = srow + it * 16;
                pa[it] = *reinterpret_cast<const float4*>(&hs[(size_t)(m0 + row) * 768 + k1 + scol]);
                pb[it] = *reinterpret_cast<const float4*>(&W[(size_t)(n0w + row) * 768 + k1 + scol]);
            }
        }
        for (int kk = 0; kk < 2; kk++) {
            bf16x8 af[4], bf[4];
            for (int i = 0; i < 4; i++) af[i] = load8s(&a_s[(wm * 64 + i * 16 + l15) * 72 + kk * 32 + qd * 8]);
            for (int j = 0; j < 4; j++) bf[j] = load8s(&b_s[(wn * 64 + j * 16 + l15) * 72 + kk * 32 + qd * 8]);
            for (int i = 0; i < 4; i++)
                for (int j = 0; j < 4; j++)
                    acc[i][j] = __builtin_amdgcn_mfma_f32_16x16x32_bf16(af[i], bf[j], acc[i][j], 0, 0, 0);
        }
    }
    __syncthreads();
    int b = m0 >> 10, l0b = m0 & 1023;
    if (which != 2) {
        float qscale = (which == 0) ? 0.125f : 1.0f;
        for (int i = 0; i < 4; i++) {
            int m_loc = wm * 64 + i * 16 + qd * 4;
            for (int j = 0; j < 4; j++) {
                int n_loc = wn * 64 + j * 16 + l15;
                float bv_ = bias[n0w + n_loc];
                for (int r = 0; r < 4; r++)
                    smem[(m_loc + r) * 136 + n_loc] = f2b((acc[i][j][r] + bv_) * qscale);
            }
        }
        __syncthreads();
        u16* dstbuf = (which == 0) ? Qa : Ka;
        for (int it = 0; it < 8; it++) {
            int c = tid + it * 256;
            int row = c >> 4, col = (c & 15) * 8;
            u32x4 w = *reinterpret_cast<u32x4*>(&smem[row * 136 + col]);
            int nn = n0w + col;
            int h = nn >> 6, d = nn & 63;
            size_t dst = ((size_t)(b * NH + h) * LL + (l0b + row)) * KAUG + d;
            *reinterpret_cast<u32x4*>(&dstbuf[dst]) = w;
        }
    } else {
        for (int i = 0; i < 4; i++) {
            int m_loc = wm * 64 + i * 16 + qd * 4;
            for (int j = 0; j < 4; j++) {
                int n_loc = wn * 64 + j * 16 + l15;
                float bv_ = bias[n0w + n_loc];
                for (int r = 0; r < 4; r++)
                    smem[n_loc * 136 + (m_loc + r)] = f2b(acc[i][j][r] + bv_);
            }
        }
        __syncthreads();
        for (int it = 0; it < 8; it++) {
            int c = tid + it * 256;
            int n = c >> 4, m_off = (c & 15) * 8;
            u32x4 w = *reinterpret_cast<u32x4*>(&smem[n * 136 + m_off]);
            int nn = n0w + n;
            int h = nn >> 6, d = nn & 63;
            size_t dst = ((size_t)(b * NH + h) * HD + d) * LL + (l0b + m_off);
            *reinterpret_cast<u32x4*>(&Vt[dst]) = w;
        }
    }
}

// ---------------------------------------------------------------- A3: histogram + pe = counts @ node_emb
__global__ __launch_bounds__(256) void k_pe(const int* __restrict__ rw,
                                            const int* __restrict__ arw,
                                            const float* __restrict__ node_emb,
                                            u16* __restrict__ Qa, u16* __restrict__ Ka) {
    int m = blockIdx.x;                  // b*L + l
    __shared__ int hist[64];
    __shared__ float c1[32], c2[32];
    int t = threadIdx.x;
    if (t < 64) hist[t] = 0;
    __syncthreads();
    if (t < 128) atomicAdd(&hist[rw[m * 128 + t] & 31], 1);
    else         atomicAdd(&hist[32 + (arw[m * 128 + (t - 128)] & 31)], 1);
    __syncthreads();
    if (t < 64) {
        if (t < 32) c1[t] = (float)hist[t];
        else        c2[t - 32] = (float)hist[t];
    }
    __syncthreads();
    int b = m >> 10, l = m & 1023;
    for (int c = t; c < 768; c += 256) {
        float s1 = 0.f, s2 = 0.f;
        for (int v = 0; v < 30; v++) {
            float ne = node_emb[v * 768 + c];
            s1 += c1[v] * ne;
            s2 += c2[v] * ne;
        }
        int h = c >> 6, d = c & 63;
        size_t base = ((size_t)(b * NH + h) * LL + l) * KAUG;
        u16 e1 = f2b(s1), e2 = f2b(s2);
        Qa[base + 64 + d] = e1;  Ka[base + 64 + d] = e1;
        Qa[base + 128 + d] = e2; Ka[base + 128 + d] = e2;
    }
}

// ---------------------------------------------------------------- B: fused MFMA flash attention
// 2-D grid (natural dispatch — r10's XCD swizzle measured WORSE: 6MB multi-head
// K/V working set blew 4MB L2). K/V staging is register-prefetched one j-tile
// ahead so global latency overlaps MFMA+softmax instead of draining at barrier.
__global__ __launch_bounds__(256) void k_attn(const u16* __restrict__ Qa, const u16* __restrict__ Ka,
                                              const u16* __restrict__ Vt,
                                              const int* __restrict__ distance,
                                              const float* __restrict__ dist_emb,
                                              const float* __restrict__ mask,
                                              void* __restrict__ outv, int f32mode) {
    __shared__ __align__(16) u16 ka_s[64][200];
    __shared__ __align__(16) u16 vt_s[64][72];
    __shared__ __align__(16) u16 p_s[4][16][72];
    __shared__ float distcol[2048];

    int itile = blockIdx.x;              // 0..15
    int bh = blockIdx.y;                 // 0..47
    int b = bh / NH, h = bh % NH;
    int tid = threadIdx.x, wave = tid >> 6, lane = tid & 63, l15 = lane & 15, qd = lane >> 4;

    const u16* Qh = Qa + (size_t)bh * LL * KAUG;
    const u16* Kh = Ka + (size_t)bh * LL * KAUG;
    const u16* Vh = Vt + (size_t)bh * HD * LL;     // V^T: [d][1024]
    const int* distb = distance + (size_t)b * LL * LL;
    const float* maskb = mask + (size_t)b * LL;

    for (int t = tid; t < 2048; t += 256) distcol[t] = dist_emb[t * NH + h];

    // per-thread staging coords
    int krow = (tid * 6 + 0) / 24;       // unused helper removed; compute per-it below
    (void)krow;

    int i0 = itile * 64 + wave * 16;
    bf16x8 aq[6];
    for (int ks = 0; ks < 6; ks++)
        aq[ks] = load8s(&Qh[(size_t)(i0 + l15) * KAUG + ks * 32 + qd * 8]);

    f32x4 o[4];
    for (int i = 0; i < 4; i++) o[i] = f32x4{0.f, 0.f, 0.f, 0.f};
    float m_i[4], l_i[4];
    for (int r = 0; r < 4; r++) { m_i[r] = -1e30f; l_i[r] = 0.f; }

    // ---- register prefetch: K/V tile 0 + dist/mask tile 0
    u32x4 kbuf[6], vbuf[2];
#pragma unroll
    for (int it = 0; it < 6; it++) {
        int c = tid + it * 256;
        int row = c / 24, col = (c % 24) * 8;
        kbuf[it] = *reinterpret_cast<const u32x4*>(&Kh[(size_t)row * KAUG + col]);
    }
#pragma unroll
    for (int it = 0; it < 2; it++) {
        int c = tid + it * 256;
        int d = c >> 3, col = (c & 7) * 8;
        vbuf[it] = *reinterpret_cast<const u32x4*>(&Vh[(size_t)d * LL + col]);
    }
    int dpre[16]; float mpre[4];
    for (int nf = 0; nf < 4; nf++) {
        int j_abs = nf * 16 + l15;
        mpre[nf] = maskb[j_abs];
        for (int r = 0; r < 4; r++)
            dpre[nf * 4 + r] = distb[(size_t)(i0 + qd * 4 + r) * LL + j_abs];
    }

    for (int jt = 0; jt < 16; jt++) {
        int j0 = jt * 64;
        __syncthreads();                 // prior tile's LDS reads done
        // dump prefetched K/V regs -> LDS (fast, no global latency here)
#pragma unroll
        for (int it = 0; it < 6; it++) {
            int c = tid + it * 256;
            int row = c / 24, col = (c % 24) * 8;
            *reinterpret_cast<u32x4*>(&ka_s[row][col]) = kbuf[it];
        }
#pragma unroll
        for (int it = 0; it < 2; it++) {
            int c = tid + it * 256;
            int d = c >> 3, col = (c & 7) * 8;
            *reinterpret_cast<u32x4*>(&vt_s[d][col]) = vbuf[it];
        }
        __syncthreads();
        // snapshot current dist/mask, then issue next tile's long-latency loads
        int dcur[16]; float mcur[4];
        for (int u_ = 0; u_ < 16; u_++) dcur[u_] = dpre[u_];
        for (int u_ = 0; u_ < 4; u_++)  mcur[u_] = mpre[u_];
        if (jt < 15) {
            int j0n = j0 + 64;
#pragma unroll
            for (int it = 0; it < 6; it++) {
                int c = tid + it * 256;
                int row = c / 24, col = (c % 24) * 8;
                kbuf[it] = *reinterpret_cast<const u32x4*>(&Kh[(size_t)(j0n + row) * KAUG + col]);
            }
#pragma unroll
            for (int it = 0; it < 2; it++) {
                int c = tid + it * 256;
                int d = c >> 3, col = (c & 7) * 8;
                vbuf[it] = *reinterpret_cast<const u32x4*>(&Vh[(size_t)d * LL + j0n + col]);
            }
            for (int nf = 0; nf < 4; nf++) {
                int j_abs = j0n + nf * 16 + l15;
                mpre[nf] = maskb[j_abs];
                for (int r = 0; r < 4; r++)
                    dpre[nf * 4 + r] = distb[(size_t)(i0 + qd * 4 + r) * LL + j_abs];
            }
        }

        // S = Qa * Ka^T (16x64/wave)
        f32x4 s[4];
        for (int nf = 0; nf < 4; nf++) {
            f32x4 accv = f32x4{0.f, 0.f, 0.f, 0.f};
            for (int ks = 0; ks < 6; ks++) {
                bf16x8 bfrag = load8s(&ka_s[nf * 16 + l15][ks * 32 + qd * 8]);
                accv = __builtin_amdgcn_mfma_f32_16x16x32_bf16(aq[ks], bfrag, accv, 0, 0, 0);
            }
            s[nf] = accv;
        }
        for (int nf = 0; nf < 4; nf++)
            for (int r = 0; r < 4; r++)
                s[nf][r] += distcol[dcur[nf * 4 + r] + 1] + mcur[nf];
        // online softmax
        float mx[4];
        for (int r = 0; r < 4; r++) {
            float v = fmaxf(fmaxf(s[0][r], s[1][r]), fmaxf(s[2][r], s[3][r]));
            for (int off = 1; off < 16; off <<= 1) v = fmaxf(v, __shfl_xor(v, off));
            mx[r] = v;
        }
        float alpha[4], rs[4];
        for (int r = 0; r < 4; r++) {
            float mnew = fmaxf(m_i[r], mx[r]);
            alpha[r] = __expf(m_i[r] - mnew);
            m_i[r] = mnew;
            rs[r] = 0.f;
        }
        for (int nf = 0; nf < 4; nf++)
            for (int r = 0; r < 4; r++) {
                float p = __expf(s[nf][r] - m_i[r]);
                rs[r] += p;
                p_s[wave][qd * 4 + r][nf * 16 + l15] = f2b(p);
            }
        for (int r = 0; r < 4; r++) {
            float v = rs[r];
            for (int off = 1; off < 16; off <<= 1) v += __shfl_xor(v, off);
            l_i[r] = l_i[r] * alpha[r] + v;
        }
        for (int df = 0; df < 4; df++)
            for (int r = 0; r < 4; r++) o[df][r] *= alpha[r];
        // p_s is per-wave; wave-local DS ordering + compiler fence suffice
        __builtin_amdgcn_sched_barrier(0);
        asm volatile("" ::: "memory");
        for (int kstep = 0; kstep < 2; kstep++) {
            bf16x8 ap = load8s(&p_s[wave][l15][kstep * 32 + qd * 8]);
            for (int df = 0; df < 4; df++) {
                bf16x8 bv_ = load8s(&vt_s[df * 16 + l15][kstep * 32 + qd * 8]);
                o[df] = __builtin_amdgcn_mfma_f32_16x16x32_bf16(ap, bv_, o[df], 0, 0, 0);
            }
        }
    }
    for (int df = 0; df < 4; df++) {
        int d = df * 16 + l15;
        for (int r = 0; r < 4; r++) {
            int i_abs = i0 + qd * 4 + r;
            float v = o[df][r] / l_i[r];
            size_t idx = ((size_t)(b * LL) + i_abs) * HID + h * 64 + d;
            if (f32mode) ((float*)outv)[idx] = v;
            else         ((u16*)outv)[idx] = f2b(v);
        }
    }
}

// ---------------------------------------------------------------- launch
extern "C" void kernel_launch(void* const* d_in, const int* in_sizes, int n_in,
                              void* d_out, int out_size, void* d_ws, size_t ws_size,
                              hipStream_t stream) {
    const float* hs       = (const float*)d_in[0];
    const float* mask     = (const float*)d_in[1];
    const float* Wq       = (const float*)d_in[2];
    const float* bq       = (const float*)d_in[3];
    const float* Wk       = (const float*)d_in[4];
    const float* bk       = (const float*)d_in[5];
    const float* Wv       = (const float*)d_in[6];
    const float* bv       = (const float*)d_in[7];
    const float* node_emb = (const float*)d_in[8];
    const float* dist_emb = (const float*)d_in[9];
    const int* distance   = (const int*)d_in[10];
    const int* rw         = (const int*)d_in[11];
    const int* arw        = (const int*)d_in[12];

    int f32mode = 0;
    {
        hipDeviceptr_t base = nullptr; size_t sz = 0;
        if (hipMemGetAddressRange(&base, &sz, (hipDeviceptr_t)d_out) == hipSuccess) {
            size_t off = (size_t)((char*)d_out - (char*)base);
            if (sz - off >= (size_t)out_size * 4u) f32mode = 1;
        }
    }

    u16* Qa = (u16*)d_ws;                            // 48*1024*192 bf16
    u16* Ka = Qa + (size_t)NBH * LL * KAUG;
    u16* Vt = Ka + (size_t)NBH * LL * KAUG;          // V^T: 48*64*1024 bf16

    k_qkv<<<dim3(32, 18), dim3(256), 0, stream>>>(hs, Wq, Wk, Wv, bq, bk, bv, Qa, Ka, Vt);
    k_pe<<<dim3(4096), dim3(256), 0, stream>>>(rw, arw, node_emb, Qa, Ka);
    k_attn<<<dim3(16, 48), dim3(256), 0, stream>>>(Qa, Ka, Vt, distance, dist_emb, mask, d_out, f32mode);
}